// Round 2
// baseline (309.375 us; speedup 1.0000x reference)
//
#include <hip/hip_runtime.h>

// Constant-address-space pointer: forces s_load (SMEM pipe) for wave-uniform
// reads, freeing the VALU to do pure fma with an SGPR broadcast operand.
#define CFLOAT const __attribute__((address_space(4))) float
#define AS4(p) ((CFLOAT*)(unsigned long long)(p))

// Broadcast lane `l`'s value of v to all lanes via v_readlane (SGPR result).
__device__ __forceinline__ float bcast(float v, int l) {
    return __int_as_float(__builtin_amdgcn_readlane(__float_as_int(v), l));
}

// dot(m[0..63], src[lane 0..63]) per lane: 64 readlane broadcasts + 64 fma,
// grouped 8-wide so every readlane->use distance is ~8 instrs (clears the
// VALU-writes-SGPR -> VALU-reads-SGPR hazard window), 8 independent chains.
__device__ __forceinline__ float dotb(const float (&m)[64], float src) {
    float a0=0.f,a1=0.f,a2=0.f,a3=0.f,a4=0.f,a5=0.f,a6=0.f,a7=0.f;
    #pragma unroll
    for (int g = 0; g < 8; ++g) {
        const int q = g * 8;
        const float s0=bcast(src,q+0), s1=bcast(src,q+1),
                    s2=bcast(src,q+2), s3=bcast(src,q+3),
                    s4=bcast(src,q+4), s5=bcast(src,q+5),
                    s6=bcast(src,q+6), s7=bcast(src,q+7);
        a0=fmaf(m[q+0],s0,a0); a1=fmaf(m[q+1],s1,a1);
        a2=fmaf(m[q+2],s2,a2); a3=fmaf(m[q+3],s3,a3);
        a4=fmaf(m[q+4],s4,a4); a5=fmaf(m[q+5],s5,a5);
        a6=fmaf(m[q+6],s6,a6); a7=fmaf(m[q+7],s7,a7);
    }
    return ((a0+a1)+(a2+a3))+((a4+a5)+(a6+a7));
}

// ---------------------------------------------------------------------------
// Stage 1: per-batch GD solve. One wave per batch; H loaded from HBM exactly
// once (coalesced column pass), row copy built via XOR-swizzled LDS transpose
// (element (r,c) stored at r*64 + (c ^ (r&31)): both write and read patterns
// are 2-way bank aliasing = free).
// ---------------------------------------------------------------------------
__global__ __launch_bounds__(256) void gd_solve(
    const float* __restrict__ y,
    const float* __restrict__ H,
    const float* __restrict__ x0,
    const float* __restrict__ step_size,
    const int*   __restrict__ iters,
    float* __restrict__ z_out)
{
    const int lane = threadIdx.x & 63;
    const int wave = threadIdx.x >> 6;
    const int b = blockIdx.x * 4 + wave;
    const float* __restrict__ Hb = H + (size_t)b * 4096;

    __shared__ float tile[4][4096];
    float* __restrict__ tl = tile[wave];

    // Coalesced column pass: hcol[r] = H[b][r][lane]; mirror into LDS swizzled.
    float hcol[64];
    #pragma unroll
    for (int r = 0; r < 64; ++r) {
        hcol[r] = Hb[r * 64 + lane];
        tl[r * 64 + (lane ^ (r & 31))] = hcol[r];
    }

    const float yv = y[b * 64 + lane];
    const float hty = dotb(hcol, yv);      // overlaps the LDS writes
    const float ts = 2.0f * step_size[0];
    const int n_it = iters[0];
    float xv = x0[b * 64 + lane];

    __syncthreads();

    // Row copy from LDS: hrow[t] = H[b][lane][t]
    float hrow[64];
    const int msk = lane & 31;
    #pragma unroll
    for (int t = 0; t < 64; ++t)
        hrow[t] = tl[lane * 64 + (t ^ msk)];

    for (int it = 0; it < n_it; ++it) {
        const float v = dotb(hrow, xv);    // v = H x
        const float w = dotb(hcol, v);     // w = H^T v = HtH x
        xv = fmaf(ts, hty - w, xv);
    }
    z_out[b * 64 + lane] = xv;
}

// ---------------------------------------------------------------------------
// Stage 2: h_new[b][j] = relu(z[b]·W_ih[j] + b_ih[j] + h[b]·W_hh[j] + b_hh[j])
// Thread j holds W rows in VGPRs; z/h rows read via addrspace(4) (s_load) so
// the broadcast operand comes from the scalar pipe. 4 independent fma chains.
// ---------------------------------------------------------------------------
#define NB1 16
__global__ __launch_bounds__(256) void rnn_cell(
    const float* __restrict__ z,
    const float* __restrict__ h,
    const float* __restrict__ W_ih,
    const float* __restrict__ W_hh,
    const float* __restrict__ b_ih,
    const float* __restrict__ b_hh,
    float* __restrict__ h_new)
{
    const int j  = threadIdx.x;            // 0..255 output feature
    const int b0 = blockIdx.x * NB1;

    float wih[64];
    #pragma unroll
    for (int k = 0; k < 16; ++k) {
        const float4 t4 = *reinterpret_cast<const float4*>(W_ih + j * 64 + k * 4);
        wih[4*k+0]=t4.x; wih[4*k+1]=t4.y; wih[4*k+2]=t4.z; wih[4*k+3]=t4.w;
    }
    const float bias = b_ih[j] + b_hh[j];

    float acc[NB1];
    #pragma unroll
    for (int b = 0; b < NB1; b += 4) {
        CFLOAT* z0 = AS4(z + (size_t)(b0 + b) * 64);
        CFLOAT* z1 = z0 + 64;
        CFLOAT* z2 = z0 + 128;
        CFLOAT* z3 = z0 + 192;
        float a0=bias, a1=bias, a2=bias, a3=bias;
        #pragma unroll
        for (int k = 0; k < 64; ++k) {
            a0 = fmaf(wih[k], z0[k], a0);
            a1 = fmaf(wih[k], z1[k], a1);
            a2 = fmaf(wih[k], z2[k], a2);
            a3 = fmaf(wih[k], z3[k], a3);
        }
        acc[b]=a0; acc[b+1]=a1; acc[b+2]=a2; acc[b+3]=a3;
    }

    for (int c = 0; c < 4; ++c) {          // W_hh K-chunks of 64
        float whh[64];
        #pragma unroll
        for (int k = 0; k < 16; ++k) {
            const float4 t4 = *reinterpret_cast<const float4*>(W_hh + j * 256 + c * 64 + k * 4);
            whh[4*k+0]=t4.x; whh[4*k+1]=t4.y; whh[4*k+2]=t4.z; whh[4*k+3]=t4.w;
        }
        #pragma unroll
        for (int b = 0; b < NB1; b += 4) {
            CFLOAT* h0 = AS4(h + (size_t)(b0 + b) * 256 + c * 64);
            CFLOAT* h1 = h0 + 256;
            CFLOAT* h2 = h0 + 512;
            CFLOAT* h3 = h0 + 768;
            float a0=acc[b], a1=acc[b+1], a2=acc[b+2], a3=acc[b+3];
            #pragma unroll
            for (int k = 0; k < 64; ++k) {
                a0 = fmaf(whh[k], h0[k], a0);
                a1 = fmaf(whh[k], h1[k], a1);
                a2 = fmaf(whh[k], h2[k], a2);
                a3 = fmaf(whh[k], h3[k], a3);
            }
            acc[b]=a0; acc[b+1]=a1; acc[b+2]=a2; acc[b+3]=a3;
        }
    }

    #pragma unroll
    for (int b = 0; b < NB1; ++b)
        h_new[(size_t)(b0 + b) * 256 + j] = fmaxf(acc[b], 0.0f);
}

// ---------------------------------------------------------------------------
// Stage 3: x_out[b][t] = h_new[b]·w_x[t] + b_x[t]
// lane = t; each wave owns NB2 batches; h_new rows via s_load; w_x chunked.
// k-outer / batch-inner => 8 independent fma chains.
// ---------------------------------------------------------------------------
#define NB2 8
__global__ __launch_bounds__(256) void out_proj(
    const float* __restrict__ h_new,
    const float* __restrict__ w_x,
    const float* __restrict__ b_x,
    float* __restrict__ x_out)
{
    const int lane = threadIdx.x & 63;
    const int wave = threadIdx.x >> 6;
    const int b0 = (blockIdx.x * 4 + wave) * NB2;

    float acc[NB2];
    const float bx = b_x[lane];
    #pragma unroll
    for (int b = 0; b < NB2; ++b) acc[b] = bx;

    for (int c = 0; c < 4; ++c) {          // K-chunks of 64
        float wxc[64];
        #pragma unroll
        for (int k = 0; k < 16; ++k) {
            const float4 t4 = *reinterpret_cast<const float4*>(w_x + lane * 256 + c * 64 + k * 4);
            wxc[4*k+0]=t4.x; wxc[4*k+1]=t4.y; wxc[4*k+2]=t4.z; wxc[4*k+3]=t4.w;
        }
        CFLOAT* hb[NB2];
        #pragma unroll
        for (int b = 0; b < NB2; ++b)
            hb[b] = AS4(h_new + (size_t)(b0 + b) * 256 + c * 64);
        #pragma unroll
        for (int k = 0; k < 64; ++k) {
            #pragma unroll
            for (int b = 0; b < NB2; ++b)
                acc[b] = fmaf(wxc[k], hb[b][k], acc[b]);
        }
    }

    #pragma unroll
    for (int b = 0; b < NB2; ++b)
        x_out[(size_t)(b0 + b) * 64 + lane] = acc[b];
}

// ---------------------------------------------------------------------------
extern "C" void kernel_launch(void* const* d_in, const int* in_sizes, int n_in,
                              void* d_out, int out_size, void* d_ws, size_t ws_size,
                              hipStream_t stream)
{
    const float* y    = (const float*)d_in[0];
    const float* H    = (const float*)d_in[1];
    const float* x0   = (const float*)d_in[2];
    const float* h    = (const float*)d_in[3];
    const float* ss   = (const float*)d_in[4];
    const float* Wih  = (const float*)d_in[5];
    const float* Whh  = (const float*)d_in[6];
    const float* bih  = (const float*)d_in[7];
    const float* bhh  = (const float*)d_in[8];
    const float* wx   = (const float*)d_in[9];
    const float* bx   = (const float*)d_in[10];
    const int*   iters= (const int*)d_in[11];

    const int B = in_sizes[0] / 64;                 // 16384 batches
    float* x_out = (float*)d_out;                   // B*64
    float* h_new = (float*)d_out + (size_t)B * 64;  // B*256
    float* z_ws  = (float*)d_ws;                    // B*64 scratch (4 MB)

    gd_solve<<<B / 4,        256, 0, stream>>>(y, H, x0, ss, iters, z_ws);
    rnn_cell<<<B / NB1,      256, 0, stream>>>(z_ws, h, Wih, Whh, bih, bhh, h_new);
    out_proj<<<B / (4*NB2),  256, 0, stream>>>(h_new, wx, bx, x_out);
}

// Round 3
// 241.397 us; speedup vs baseline: 1.2816x; 1.2816x over previous
//
#include <hip/hip_runtime.h>

typedef short sh8  __attribute__((ext_vector_type(8)));   // 8 bf16 bit-patterns
typedef __bf16 bfv8 __attribute__((ext_vector_type(8)));
typedef float  fv4  __attribute__((ext_vector_type(4)));

__device__ __forceinline__ unsigned short f2bf(float x) {  // fp32 -> bf16 RNE
    unsigned u = __float_as_uint(x);
    return (unsigned short)((u + 0x7FFFu + ((u >> 16) & 1u)) >> 16);
}
__device__ __forceinline__ float bf2f(unsigned short b) {
    return __uint_as_float(((unsigned)b) << 16);
}
__device__ __forceinline__ fv4 mfma16(sh8 a, sh8 b, fv4 c) {
    return __builtin_amdgcn_mfma_f32_16x16x32_bf16(
        __builtin_bit_cast(bfv8, a), __builtin_bit_cast(bfv8, b), c, 0, 0, 0);
}

// ---------------------------------------------------------------------------
// Stage 1 (fused): per batch, G = HtH via bf16x2 MFMA, then 20 GD iterations
//   x += ts*(Hty - G x)  with x broadcast via uniform ds_read_b128 (DS pipe).
// One 64-thread block (1 wave) per batch.
// LDS: Ht_hi[64][72] + Ht_lo[64][72] (bf16 bits), overlaid by G[64][65] fp32,
//      plus a 64-float broadcast buffer at the tail.
// ---------------------------------------------------------------------------
#define HT_S 72
#define G_S  65

__global__ __launch_bounds__(64) void solve_fused(
    const float* __restrict__ y, const float* __restrict__ H,
    const float* __restrict__ x0, const float* __restrict__ step_size,
    const int* __restrict__ iters, float* __restrict__ z_out)
{
    __shared__ __align__(16) char ldsraw[64*HT_S*2*2 + 256];  // 18432 + 256
    short* hhi = (short*)ldsraw;                   // [64][HT_S]
    short* hlo = ((short*)ldsraw) + 64*HT_S;       // [64][HT_S]
    float* gm  = (float*)ldsraw;                   // [64][G_S] overlay (16640 B)
    float* xl  = (float*)(ldsraw + 64*HT_S*2*2);   // [64] broadcast buffer

    const int lane = threadIdx.x;
    const int b = blockIdx.x;
    const float* __restrict__ Hb = H + (size_t)b * 4096;

    // column c=lane of H, coalesced: hcol[r] = H[r][lane] = Ht[lane][r]
    float hcol[64];
    #pragma unroll
    for (int r = 0; r < 64; ++r) hcol[r] = Hb[r*64 + lane];

    // write row `lane` of Ht as bf16 hi/lo
    #pragma unroll
    for (int g = 0; g < 8; ++g) {
        sh8 vhi, vlo;
        #pragma unroll
        for (int i = 0; i < 8; ++i) {
            float x = hcol[g*8 + i];
            unsigned short hb = f2bf(x);
            vhi[i] = (short)hb;
            vlo[i] = (short)f2bf(x - bf2f(hb));
        }
        *(sh8*)(hhi + lane*HT_S + g*8) = vhi;
        *(sh8*)(hlo + lane*HT_S + g*8) = vlo;
    }

    // Hty[lane] = sum_r Ht[lane][r]*y[r], y broadcast via uniform LDS reads
    xl[lane] = y[(size_t)b*64 + lane];
    float hty;
    {
        float h0=0.f,h1=0.f,h2=0.f,h3=0.f;
        #pragma unroll
        for (int q = 0; q < 16; ++q) {
            fv4 xb = *(const fv4*)(xl + q*4);
            h0 = fmaf(hcol[q*4+0], xb[0], h0);
            h1 = fmaf(hcol[q*4+1], xb[1], h1);
            h2 = fmaf(hcol[q*4+2], xb[2], h2);
            h3 = fmaf(hcol[q*4+3], xb[3], h3);
        }
        hty = (h0+h1)+(h2+h3);
    }

    __syncthreads();

    // fragment loads: A(tile mt)=Ht rows, B(tile nt)=same formula -> shared
    const int fr = lane & 15, fg = lane >> 4;
    sh8 fhi[4][2], flo[4][2];
    #pragma unroll
    for (int tt = 0; tt < 4; ++tt)
        #pragma unroll
        for (int kk = 0; kk < 2; ++kk) {
            const int off = (tt*16 + fr)*HT_S + kk*32 + fg*8;
            fhi[tt][kk] = *(const sh8*)(hhi + off);
            flo[tt][kk] = *(const sh8*)(hlo + off);
        }

    // G = HtH in bf16x2: hi*hi + hi*lo + lo*hi, fp32 accumulate
    fv4 acc[4][4];
    #pragma unroll
    for (int mt = 0; mt < 4; ++mt)
        #pragma unroll
        for (int nt = 0; nt < 4; ++nt) {
            fv4 a = {0.f, 0.f, 0.f, 0.f};
            #pragma unroll
            for (int kk = 0; kk < 2; ++kk) {
                a = mfma16(fhi[mt][kk], fhi[nt][kk], a);
                a = mfma16(fhi[mt][kk], flo[nt][kk], a);
                a = mfma16(flo[mt][kk], fhi[nt][kk], a);
            }
            acc[mt][nt] = a;
        }

    __syncthreads();   // Ht dead; overlay with G

    // D layout (m89-verified): col = lane&15, row = (lane>>4)*4 + i
    #pragma unroll
    for (int mt = 0; mt < 4; ++mt)
        #pragma unroll
        for (int nt = 0; nt < 4; ++nt)
            #pragma unroll
            for (int i = 0; i < 4; ++i)
                gm[(mt*16 + fg*4 + i)*G_S + nt*16 + fr] = acc[mt][nt][i];

    __syncthreads();

    float gcol[64];   // gcol[s] = G[s][lane]
    #pragma unroll
    for (int s = 0; s < 64; ++s) gcol[s] = gm[s*G_S + lane];

    float xv = x0[(size_t)b*64 + lane];
    const float ts = 2.0f * step_size[0];
    const int n_it = iters[0];

    for (int it = 0; it < n_it; ++it) {
        xl[lane] = xv;                      // in-order DS, single wave: safe
        float w0=0.f,w1=0.f,w2=0.f,w3=0.f;
        #pragma unroll
        for (int q = 0; q < 16; ++q) {
            fv4 xb = *(const fv4*)(xl + q*4);   // uniform -> broadcast
            w0 = fmaf(gcol[q*4+0], xb[0], w0);
            w1 = fmaf(gcol[q*4+1], xb[1], w1);
            w2 = fmaf(gcol[q*4+2], xb[2], w2);
            w3 = fmaf(gcol[q*4+3], xb[3], w3);
        }
        xv = fmaf(ts, hty - ((w0+w1)+(w2+w3)), xv);
    }
    z_out[(size_t)b*64 + lane] = xv;
}

// ---------------------------------------------------------------------------
// Weight transposes so per-feature weight loads coalesce (runs once, tiny).
// wt_ih[k][j] = W_ih[j][k]; wt_hh[k][j] = W_hh[j][k]; wxt[k][u] = w_x[u][k]
// ---------------------------------------------------------------------------
__global__ __launch_bounds__(256) void transpose_prep(
    const float* __restrict__ Wih, const float* __restrict__ Whh,
    const float* __restrict__ wx, float* __restrict__ wt_ih,
    float* __restrict__ wt_hh, float* __restrict__ wxt)
{
    int idx = blockIdx.x*256 + threadIdx.x;
    if (idx < 64*256) {
        int k = idx >> 8, j = idx & 255;
        wt_ih[idx] = Wih[j*64 + k];
        return;
    }
    idx -= 64*256;
    if (idx < 256*256) {
        int k = idx >> 8, j = idx & 255;
        wt_hh[idx] = Whh[j*256 + k];
        return;
    }
    idx -= 256*256;
    {
        int k = idx >> 6, u = idx & 63;
        wxt[idx] = wx[u*256 + k];
    }
}

// ---------------------------------------------------------------------------
// Stage 2: h_new[b][j] = relu(z[b]·W_ih[j] + h[b]·W_hh[j] + b_ih[j] + b_hh[j])
// Thread = feature j; activations staged in LDS, read via uniform ds_read_b128
// (broadcast, DS pipe); weights coalesced from transposed copies; acc[32].
// ---------------------------------------------------------------------------
#define BT   32
#define ASTR 324

__global__ __launch_bounds__(256) void rnn_fused(
    const float* __restrict__ z, const float* __restrict__ h,
    const float* __restrict__ wt_ih, const float* __restrict__ wt_hh,
    const float* __restrict__ b_ih, const float* __restrict__ b_hh,
    float* __restrict__ h_new)
{
    __shared__ __align__(16) float act[BT*ASTR];   // 41472 B
    const int t = threadIdx.x;
    const int b0 = blockIdx.x * BT;

    #pragma unroll
    for (int i = 0; i < 2; ++i) {          // z tile: 32 x 64
        int f = t + 256*i, b = f >> 4, c = (f & 15) * 4;
        *(fv4*)(act + b*ASTR + c) = *(const fv4*)(z + (size_t)(b0+b)*64 + c);
    }
    #pragma unroll
    for (int i = 0; i < 8; ++i) {          // h tile: 32 x 256
        int f = t + 256*i, b = f >> 6, c = (f & 63) * 4;
        *(fv4*)(act + b*ASTR + 64 + c) = *(const fv4*)(h + (size_t)(b0+b)*256 + c);
    }
    __syncthreads();

    float acc[BT];
    {
        const float bias = b_ih[t] + b_hh[t];
        #pragma unroll
        for (int b = 0; b < BT; ++b) acc[b] = bias;
    }

    float w[64];
    #pragma unroll 1
    for (int kc = 0; kc < 5; ++kc) {       // k-chunks: 0 -> z, 1..4 -> h
        if (kc == 0) {
            #pragma unroll
            for (int k = 0; k < 64; ++k) w[k] = wt_ih[k*256 + t];
        } else {
            const float* wsrc = wt_hh + (size_t)(kc-1)*64*256;
            #pragma unroll
            for (int k = 0; k < 64; ++k) w[k] = wsrc[k*256 + t];
        }
        const int abase = kc*64;
        #pragma unroll
        for (int bq = 0; bq < BT; bq += 4) {
            const float* a0 = act + (bq+0)*ASTR + abase;
            const float* a1 = act + (bq+1)*ASTR + abase;
            const float* a2 = act + (bq+2)*ASTR + abase;
            const float* a3 = act + (bq+3)*ASTR + abase;
            #pragma unroll
            for (int k4 = 0; k4 < 16; ++k4) {
                fv4 v0 = *(const fv4*)(a0 + k4*4);
                fv4 v1 = *(const fv4*)(a1 + k4*4);
                fv4 v2 = *(const fv4*)(a2 + k4*4);
                fv4 v3 = *(const fv4*)(a3 + k4*4);
                #pragma unroll
                for (int u = 0; u < 4; ++u) {
                    acc[bq+0] = fmaf(w[k4*4+u], v0[u], acc[bq+0]);
                    acc[bq+1] = fmaf(w[k4*4+u], v1[u], acc[bq+1]);
                    acc[bq+2] = fmaf(w[k4*4+u], v2[u], acc[bq+2]);
                    acc[bq+3] = fmaf(w[k4*4+u], v3[u], acc[bq+3]);
                }
            }
        }
    }

    #pragma unroll
    for (int b = 0; b < BT; ++b)
        h_new[(size_t)(b0+b)*256 + t] = fmaxf(acc[b], 0.f);
}

// ---------------------------------------------------------------------------
// Stage 3: x_out[b][u] = h_new[b]·w_x[u] + b_x[u]
// lane = u; h_new tile staged in LDS (uniform b128 broadcasts); wxt coalesced.
// ---------------------------------------------------------------------------
#define CB 64

__global__ __launch_bounds__(256) void out_proj(
    const float* __restrict__ h_new, const float* __restrict__ wxt,
    const float* __restrict__ b_x, float* __restrict__ x_out)
{
    __shared__ __align__(16) float hl[CB*256];   // 65536 B
    const int t = threadIdx.x, lane = t & 63, wv = t >> 6;
    const int b0 = blockIdx.x * CB;

    #pragma unroll
    for (int i = 0; i < 16; ++i) {
        int f = t + 256*i, b = f >> 6, c = (f & 63) * 4;
        *(fv4*)(hl + b*256 + c) = *(const fv4*)(h_new + (size_t)(b0+b)*256 + c);
    }
    __syncthreads();

    float acc[16];
    {
        const float bx = b_x[lane];
        #pragma unroll
        for (int i = 0; i < 16; ++i) acc[i] = bx;
    }

    float wxc[64];
    #pragma unroll 1
    for (int kc = 0; kc < 4; ++kc) {
        #pragma unroll
        for (int k = 0; k < 64; ++k)
            wxc[k] = wxt[(size_t)(kc*64 + k)*64 + lane];
        const int bb = wv * 16;
        #pragma unroll
        for (int bq = 0; bq < 16; bq += 4) {
            const float* h0 = hl + (bb+bq+0)*256 + kc*64;
            const float* h1 = hl + (bb+bq+1)*256 + kc*64;
            const float* h2 = hl + (bb+bq+2)*256 + kc*64;
            const float* h3 = hl + (bb+bq+3)*256 + kc*64;
            #pragma unroll
            for (int k4 = 0; k4 < 16; ++k4) {
                fv4 v0 = *(const fv4*)(h0 + k4*4);
                fv4 v1 = *(const fv4*)(h1 + k4*4);
                fv4 v2 = *(const fv4*)(h2 + k4*4);
                fv4 v3 = *(const fv4*)(h3 + k4*4);
                #pragma unroll
                for (int u = 0; u < 4; ++u) {
                    acc[bq+0] = fmaf(wxc[k4*4+u], v0[u], acc[bq+0]);
                    acc[bq+1] = fmaf(wxc[k4*4+u], v1[u], acc[bq+1]);
                    acc[bq+2] = fmaf(wxc[k4*4+u], v2[u], acc[bq+2]);
                    acc[bq+3] = fmaf(wxc[k4*4+u], v3[u], acc[bq+3]);
                }
            }
        }
    }

    #pragma unroll
    for (int i = 0; i < 16; ++i)
        x_out[(size_t)(b0 + wv*16 + i)*64 + lane] = acc[i];
}

// ---------------------------------------------------------------------------
extern "C" void kernel_launch(void* const* d_in, const int* in_sizes, int n_in,
                              void* d_out, int out_size, void* d_ws, size_t ws_size,
                              hipStream_t stream)
{
    const float* y    = (const float*)d_in[0];
    const float* H    = (const float*)d_in[1];
    const float* x0   = (const float*)d_in[2];
    const float* h    = (const float*)d_in[3];
    const float* ss   = (const float*)d_in[4];
    const float* Wih  = (const float*)d_in[5];
    const float* Whh  = (const float*)d_in[6];
    const float* bih  = (const float*)d_in[7];
    const float* bhh  = (const float*)d_in[8];
    const float* wx   = (const float*)d_in[9];
    const float* bx   = (const float*)d_in[10];
    const int*   iters= (const int*)d_in[11];

    const int B = in_sizes[0] / 64;                 // 16384
    float* x_out = (float*)d_out;                   // B*64
    float* h_new = (float*)d_out + (size_t)B * 64;  // B*256

    float* zws   = (float*)d_ws;                    // B*64
    float* wt_ih = zws + (size_t)B * 64;            // 64*256
    float* wt_hh = wt_ih + 64*256;                  // 256*256
    float* wxt   = wt_hh + 256*256;                 // 256*64

    transpose_prep<<<384, 256, 0, stream>>>(Wih, Whh, wx, wt_ih, wt_hh, wxt);
    solve_fused<<<B, 64, 0, stream>>>(y, H, x0, ss, iters, zws);
    rnn_fused<<<B/BT, 256, 0, stream>>>(zws, h, wt_ih, wt_hh, bih, bhh, h_new);
    out_proj<<<B/CB, 256, 0, stream>>>(h_new, wxt, bx, x_out);
}

// Round 4
// 232.968 us; speedup vs baseline: 1.3280x; 1.0362x over previous
//
#include <hip/hip_runtime.h>

typedef short sh8  __attribute__((ext_vector_type(8)));   // 8 bf16 bit-patterns
typedef __bf16 bfv8 __attribute__((ext_vector_type(8)));
typedef float  fv4  __attribute__((ext_vector_type(4)));

__device__ __forceinline__ unsigned short f2bf(float x) {  // fp32 -> bf16 RNE
    unsigned u = __float_as_uint(x);
    return (unsigned short)((u + 0x7FFFu + ((u >> 16) & 1u)) >> 16);
}
__device__ __forceinline__ float bf2f(unsigned short b) {
    return __uint_as_float(((unsigned)b) << 16);
}
__device__ __forceinline__ fv4 mfma16(sh8 a, sh8 b, fv4 c) {
    return __builtin_amdgcn_mfma_f32_16x16x32_bf16(
        __builtin_bit_cast(bfv8, a), __builtin_bit_cast(bfv8, b), c, 0, 0, 0);
}
__device__ __forceinline__ float bcast(float v, int l) {
    return __int_as_float(__builtin_amdgcn_readlane(__float_as_int(v), l));
}

// dot(m[0..63], src[lanes]) via readlane broadcasts; 8 chains, dist-8 hazard gap.
__device__ __forceinline__ float dotb(const float (&m)[64], float src) {
    float a0=0.f,a1=0.f,a2=0.f,a3=0.f,a4=0.f,a5=0.f,a6=0.f,a7=0.f;
    #pragma unroll
    for (int g = 0; g < 8; ++g) {
        const int q = g * 8;
        const float s0=bcast(src,q+0), s1=bcast(src,q+1),
                    s2=bcast(src,q+2), s3=bcast(src,q+3),
                    s4=bcast(src,q+4), s5=bcast(src,q+5),
                    s6=bcast(src,q+6), s7=bcast(src,q+7);
        a0=fmaf(m[q+0],s0,a0); a1=fmaf(m[q+1],s1,a1);
        a2=fmaf(m[q+2],s2,a2); a3=fmaf(m[q+3],s3,a3);
        a4=fmaf(m[q+4],s4,a4); a5=fmaf(m[q+5],s5,a5);
        a6=fmaf(m[q+6],s6,a6); a7=fmaf(m[q+7],s7,a7);
    }
    return ((a0+a1)+(a2+a3))+((a4+a5)+(a6+a7));
}

// ---------------------------------------------------------------------------
// Stage 1: per batch, G = HtH via bf16x2 MFMA (LDS-staged), then 20 GD iters
// x += ts*(Hty - G x) fully in registers (readlane broadcasts, no LDS in loop).
// 128-thread blocks, 1 wave per batch, 16 KB LDS per batch:
//   bf16 planes hhi/hlo [64 rows][8 chunks of 8], chunk swizzled g^(row&7);
//   G [64][64] fp32 overlays the same region after fragment reads.
// No __syncthreads: each wave touches only its own LDS region.
// ---------------------------------------------------------------------------
#define PB 2

__global__ __launch_bounds__(128, 3) void solve_fused(
    const float* __restrict__ y, const float* __restrict__ H,
    const float* __restrict__ x0, const float* __restrict__ step_size,
    const int* __restrict__ iters, float* __restrict__ z_out)
{
    __shared__ __align__(16) char ldsraw[PB * 16384];
    const int lane = threadIdx.x & 63;
    const int wv   = threadIdx.x >> 6;
    const int b    = blockIdx.x * PB + wv;

    short* hhi = (short*)(ldsraw + wv * 16384);   // [64][64] shorts, swizzled
    short* hlo = hhi + 4096;                      // second 8 KB plane
    float* gm  = (float*)(ldsraw + wv * 16384);   // [64][64] fp32 overlay

    const float* __restrict__ Hb = H + (size_t)b * 4096;

    // hcol[r] = H[r][lane] = Ht[lane][r]  (coalesced, single HBM pass)
    float hcol[64];
    #pragma unroll
    for (int r = 0; r < 64; ++r) hcol[r] = Hb[r * 64 + lane];

    // Hty[lane] = sum_r Ht[lane][r] * y[r]  (exact fp32, readlane broadcasts)
    const float yv = y[(size_t)b * 64 + lane];
    const float hty = dotb(hcol, yv);

    // convert row `lane` of Ht to bf16 hi/lo, write swizzled 16B chunks
    #pragma unroll
    for (int g = 0; g < 8; ++g) {
        sh8 vhi, vlo;
        #pragma unroll
        for (int i = 0; i < 8; ++i) {
            float xq = hcol[g*8 + i];
            unsigned short hb = f2bf(xq);
            vhi[i] = (short)hb;
            vlo[i] = (short)f2bf(xq - bf2f(hb));
        }
        const int sw = (g ^ (lane & 7)) * 8;
        *(sh8*)(hhi + lane * 64 + sw) = vhi;
        *(sh8*)(hlo + lane * 64 + sw) = vlo;
    }

    // fragments: A(tile)=B(tile)=Ht rows (G symmetric); row=16*tt+fr, k-chunk
    const int fr = lane & 15, fg = lane >> 4;
    sh8 fhi[4][2], flo[4][2];
    #pragma unroll
    for (int tt = 0; tt < 4; ++tt)
        #pragma unroll
        for (int kk = 0; kk < 2; ++kk) {
            const int row = tt * 16 + fr;
            const int ch  = ((kk * 4 + fg) ^ (fr & 7)) * 8;
            fhi[tt][kk] = *(const sh8*)(hhi + row * 64 + ch);
            flo[tt][kk] = *(const sh8*)(hlo + row * 64 + ch);
        }

    // G = HtH bf16x2: hi*hi + hi*lo + lo*hi, fp32 accumulate (48 MFMA)
    fv4 acc[4][4];
    #pragma unroll
    for (int mt = 0; mt < 4; ++mt)
        #pragma unroll
        for (int nt = 0; nt < 4; ++nt) {
            fv4 a = {0.f, 0.f, 0.f, 0.f};
            #pragma unroll
            for (int kk = 0; kk < 2; ++kk) {
                a = mfma16(fhi[mt][kk], fhi[nt][kk], a);
                a = mfma16(fhi[mt][kk], flo[nt][kk], a);
                a = mfma16(flo[mt][kk], fhi[nt][kk], a);
            }
            acc[mt][nt] = a;
        }

    // drain fragment reads before overwriting the region with G
    asm volatile("s_waitcnt lgkmcnt(0)" ::: "memory");

    // D layout (m89): col = lane&15, row = (lane>>4)*4 + i
    #pragma unroll
    for (int mt = 0; mt < 4; ++mt)
        #pragma unroll
        for (int nt = 0; nt < 4; ++nt)
            #pragma unroll
            for (int i = 0; i < 4; ++i)
                gm[(mt*16 + fg*4 + i) * 64 + nt*16 + fr] = acc[mt][nt][i];

    // gcol[s] = G[s][lane]  (= G[lane][s] by symmetry)
    float gcol[64];
    #pragma unroll
    for (int s = 0; s < 64; ++s) gcol[s] = gm[s * 64 + lane];

    float xv = x0[(size_t)b * 64 + lane];
    const float ts = 2.0f * step_size[0];
    const int n_it = iters[0];

    for (int it = 0; it < n_it; ++it)
        xv = fmaf(ts, hty - dotb(gcol, xv), xv);

    z_out[(size_t)b * 64 + lane] = xv;
}

// ---------------------------------------------------------------------------
// Weight transposes so per-feature weight loads coalesce (runs once, tiny).
// ---------------------------------------------------------------------------
__global__ __launch_bounds__(256) void transpose_prep(
    const float* __restrict__ Wih, const float* __restrict__ Whh,
    const float* __restrict__ wx, float* __restrict__ wt_ih,
    float* __restrict__ wt_hh, float* __restrict__ wxt)
{
    int idx = blockIdx.x*256 + threadIdx.x;
    if (idx < 64*256) {
        int k = idx >> 8, j = idx & 255;
        wt_ih[idx] = Wih[j*64 + k];
        return;
    }
    idx -= 64*256;
    if (idx < 256*256) {
        int k = idx >> 8, j = idx & 255;
        wt_hh[idx] = Whh[j*256 + k];
        return;
    }
    idx -= 256*256;
    {
        int k = idx >> 6, u = idx & 63;
        wxt[idx] = wx[u*256 + k];
    }
}

// ---------------------------------------------------------------------------
// Stage 2: h_new[b][j] = relu(z[b]·W_ih[j] + h[b]·W_hh[j] + b_ih[j] + b_hh[j])
// ---------------------------------------------------------------------------
#define BT   32
#define ASTR 324

__global__ __launch_bounds__(256) void rnn_fused(
    const float* __restrict__ z, const float* __restrict__ h,
    const float* __restrict__ wt_ih, const float* __restrict__ wt_hh,
    const float* __restrict__ b_ih, const float* __restrict__ b_hh,
    float* __restrict__ h_new)
{
    __shared__ __align__(16) float act[BT*ASTR];   // 41472 B
    const int t = threadIdx.x;
    const int b0 = blockIdx.x * BT;

    #pragma unroll
    for (int i = 0; i < 2; ++i) {          // z tile: 32 x 64
        int f = t + 256*i, b = f >> 4, c = (f & 15) * 4;
        *(fv4*)(act + b*ASTR + c) = *(const fv4*)(z + (size_t)(b0+b)*64 + c);
    }
    #pragma unroll
    for (int i = 0; i < 8; ++i) {          // h tile: 32 x 256
        int f = t + 256*i, b = f >> 6, c = (f & 63) * 4;
        *(fv4*)(act + b*ASTR + 64 + c) = *(const fv4*)(h + (size_t)(b0+b)*256 + c);
    }
    __syncthreads();

    float acc[BT];
    {
        const float bias = b_ih[t] + b_hh[t];
        #pragma unroll
        for (int b = 0; b < BT; ++b) acc[b] = bias;
    }

    float w[64];
    #pragma unroll 1
    for (int kc = 0; kc < 5; ++kc) {       // k-chunks: 0 -> z, 1..4 -> h
        if (kc == 0) {
            #pragma unroll
            for (int k = 0; k < 64; ++k) w[k] = wt_ih[k*256 + t];
        } else {
            const float* wsrc = wt_hh + (size_t)(kc-1)*64*256;
            #pragma unroll
            for (int k = 0; k < 64; ++k) w[k] = wsrc[k*256 + t];
        }
        const int abase = kc*64;
        #pragma unroll
        for (int bq = 0; bq < BT; bq += 4) {
            const float* a0 = act + (bq+0)*ASTR + abase;
            const float* a1 = act + (bq+1)*ASTR + abase;
            const float* a2 = act + (bq+2)*ASTR + abase;
            const float* a3 = act + (bq+3)*ASTR + abase;
            #pragma unroll
            for (int k4 = 0; k4 < 16; ++k4) {
                fv4 v0 = *(const fv4*)(a0 + k4*4);
                fv4 v1 = *(const fv4*)(a1 + k4*4);
                fv4 v2 = *(const fv4*)(a2 + k4*4);
                fv4 v3 = *(const fv4*)(a3 + k4*4);
                #pragma unroll
                for (int u = 0; u < 4; ++u) {
                    acc[bq+0] = fmaf(w[k4*4+u], v0[u], acc[bq+0]);
                    acc[bq+1] = fmaf(w[k4*4+u], v1[u], acc[bq+1]);
                    acc[bq+2] = fmaf(w[k4*4+u], v2[u], acc[bq+2]);
                    acc[bq+3] = fmaf(w[k4*4+u], v3[u], acc[bq+3]);
                }
            }
        }
    }

    #pragma unroll
    for (int b = 0; b < BT; ++b)
        h_new[(size_t)(b0+b)*256 + t] = fmaxf(acc[b], 0.f);
}

// ---------------------------------------------------------------------------
// Stage 3: x_out[b][u] = h_new[b]·w_x[u] + b_x[u]
// ---------------------------------------------------------------------------
#define CB 64

__global__ __launch_bounds__(256) void out_proj(
    const float* __restrict__ h_new, const float* __restrict__ wxt,
    const float* __restrict__ b_x, float* __restrict__ x_out)
{
    __shared__ __align__(16) float hl[CB*256];   // 65536 B
    const int t = threadIdx.x, lane = t & 63, wv = t >> 6;
    const int b0 = blockIdx.x * CB;

    #pragma unroll
    for (int i = 0; i < 16; ++i) {
        int f = t + 256*i, b = f >> 6, c = (f & 63) * 4;
        *(fv4*)(hl + b*256 + c) = *(const fv4*)(h_new + (size_t)(b0+b)*256 + c);
    }
    __syncthreads();

    float acc[16];
    {
        const float bx = b_x[lane];
        #pragma unroll
        for (int i = 0; i < 16; ++i) acc[i] = bx;
    }

    float wxc[64];
    #pragma unroll 1
    for (int kc = 0; kc < 4; ++kc) {
        #pragma unroll
        for (int k = 0; k < 64; ++k)
            wxc[k] = wxt[(size_t)(kc*64 + k)*64 + lane];
        const int bb = wv * 16;
        #pragma unroll
        for (int bq = 0; bq < 16; bq += 4) {
            const float* h0 = hl + (bb+bq+0)*256 + kc*64;
            const float* h1 = hl + (bb+bq+1)*256 + kc*64;
            const float* h2 = hl + (bb+bq+2)*256 + kc*64;
            const float* h3 = hl + (bb+bq+3)*256 + kc*64;
            #pragma unroll
            for (int k4 = 0; k4 < 16; ++k4) {
                fv4 v0 = *(const fv4*)(h0 + k4*4);
                fv4 v1 = *(const fv4*)(h1 + k4*4);
                fv4 v2 = *(const fv4*)(h2 + k4*4);
                fv4 v3 = *(const fv4*)(h3 + k4*4);
                #pragma unroll
                for (int u = 0; u < 4; ++u) {
                    acc[bq+0] = fmaf(wxc[k4*4+u], v0[u], acc[bq+0]);
                    acc[bq+1] = fmaf(wxc[k4*4+u], v1[u], acc[bq+1]);
                    acc[bq+2] = fmaf(wxc[k4*4+u], v2[u], acc[bq+2]);
                    acc[bq+3] = fmaf(wxc[k4*4+u], v3[u], acc[bq+3]);
                }
            }
        }
    }

    #pragma unroll
    for (int i = 0; i < 16; ++i)
        x_out[(size_t)(b0 + wv*16 + i)*64 + lane] = acc[i];
}

// ---------------------------------------------------------------------------
extern "C" void kernel_launch(void* const* d_in, const int* in_sizes, int n_in,
                              void* d_out, int out_size, void* d_ws, size_t ws_size,
                              hipStream_t stream)
{
    const float* y    = (const float*)d_in[0];
    const float* H    = (const float*)d_in[1];
    const float* x0   = (const float*)d_in[2];
    const float* h    = (const float*)d_in[3];
    const float* ss   = (const float*)d_in[4];
    const float* Wih  = (const float*)d_in[5];
    const float* Whh  = (const float*)d_in[6];
    const float* bih  = (const float*)d_in[7];
    const float* bhh  = (const float*)d_in[8];
    const float* wx   = (const float*)d_in[9];
    const float* bx   = (const float*)d_in[10];
    const int*   iters= (const int*)d_in[11];

    const int B = in_sizes[0] / 64;                 // 16384
    float* x_out = (float*)d_out;                   // B*64
    float* h_new = (float*)d_out + (size_t)B * 64;  // B*256

    float* zws   = (float*)d_ws;                    // B*64
    float* wt_ih = zws + (size_t)B * 64;            // 64*256
    float* wt_hh = wt_ih + 64*256;                  // 256*256
    float* wxt   = wt_hh + 256*256;                 // 256*64

    transpose_prep<<<384, 256, 0, stream>>>(Wih, Whh, wx, wt_ih, wt_hh, wxt);
    solve_fused<<<B/PB, 128, 0, stream>>>(y, H, x0, ss, iters, zws);
    rnn_fused<<<B/BT, 256, 0, stream>>>(zws, h, wt_ih, wt_hh, bih, bhh, h_new);
    out_proj<<<B/CB, 256, 0, stream>>>(h_new, wxt, bx, x_out);
}